// Round 2
// baseline (2680.842 us; speedup 1.0000x reference)
//
#include <hip/hip_runtime.h>
#include <hip/hip_bf16.h>

#define N_ATOMS 15000
#define N_EDGES 300000
#define FDIM 128
#define NRBF 20
#define CUTOFF 5.0f
#define PI_F 3.14159265358979323846f

typedef __hip_bfloat16 bf16;

__device__ __forceinline__ float b2f(bf16 v) { return __bfloat162float(v); }
__device__ __forceinline__ float siluf(float x) { return x / (1.0f + __expf(-x)); }

// ---- converted-parameter offsets (f32 elements) -----------------------------
// order: r_ij, emb, fW, fb, iW1, ib1, iW2, ib2, mW, mb, aW1, ab1, aW2, ab2
__device__ __constant__ int c_off[15] = {
    0, 900000, 912800, 935840, 936992, 986144, 986528, 1133984,
    1135136, 1233440, 1234208, 1332512, 1332896, 1480352, 1481504};
#define P_TOTAL 1481504
#define P_RIJ 0
#define P_EMB 900000
#define P_FW  912800
#define P_FB  935840
#define P_IW1 936992
#define P_IB1 986144
#define P_IW2 986528
#define P_IB2 1133984
#define P_MW  1135136
#define P_MB  1233440
#define P_AW1 1234208
#define P_AB1 1332512
#define P_AW2 1332896
#define P_AB2 1480352

// ---------------------------------------------------------------------------
// Detect whether float tensors are stored as bf16 (flag=1) or f32 (flag=0).
// bf16 N(0,1.5) data: ~100% of |v| in [2^-10,16]. f32 data read as bf16:
// even indices are uniform garbage (~5.5% in range) -> frac ~0.53.
// ---------------------------------------------------------------------------
__global__ void detect_dtype(const void* __restrict__ r_ij, int* __restrict__ flag) {
    __shared__ int cnt;
    if (threadIdx.x == 0) cnt = 0;
    __syncthreads();
    const bf16* p = (const bf16*)r_ij;
    float v = fabsf(b2f(p[threadIdx.x]));
    int ok = (v > 0.0009765625f && v < 16.0f) ? 1 : 0;  // NaN -> false
    atomicAdd(&cnt, ok);
    __syncthreads();
    if (threadIdx.x == 0) flag[0] = (cnt > 204) ? 1 : 0;  // >80% of 256
}

// ---------------------------------------------------------------------------
// Up-convert all 14 float tensors into one contiguous f32 parameter block.
// ---------------------------------------------------------------------------
struct CvtArgs { const void* src[14]; };

__global__ void convert_all(CvtArgs args, float* __restrict__ dst,
                            const int* __restrict__ flag) {
    int i = blockIdx.x * blockDim.x + threadIdx.x;
    if (i >= P_TOTAL) return;
    bool isbf = flag[0] != 0;
    int s = 0;
    while (i >= c_off[s + 1]) s++;
    int k = i - c_off[s];
    float v = isbf ? b2f(((const bf16*)args.src[s])[k])
                   : ((const float*)args.src[s])[k];
    dst[i] = v;
}

// ---------------------------------------------------------------------------
// q[a][f] = embedding[z[a]][f]
// ---------------------------------------------------------------------------
__global__ void init_q(const int* __restrict__ zn, const float* __restrict__ emb,
                       float* __restrict__ q) {
    int idx = blockIdx.x * blockDim.x + threadIdx.x;
    if (idx >= N_ATOMS * FDIM) return;
    int a = idx >> 7;
    int f = idx & 127;
    q[idx] = emb[zn[a] * FDIM + f];
}

// ---------------------------------------------------------------------------
// Per-atom: h = silu(q @ W1 + b1); x = h @ W2 + b2   (x: N_ATOMS x 384, f32)
// ---------------------------------------------------------------------------
__global__ __launch_bounds__(128) void inter_mlp(
    const float* __restrict__ q,
    const float* __restrict__ W1, const float* __restrict__ b1,
    const float* __restrict__ W2, const float* __restrict__ b2,
    float* __restrict__ x) {
    int a = blockIdx.x;
    int f = threadIdx.x;
    __shared__ float sq[FDIM];
    __shared__ float sh[FDIM];
    sq[f] = q[(size_t)a * FDIM + f];
    __syncthreads();
    float acc = b1[f];
#pragma unroll 4
    for (int k = 0; k < FDIM; k++) acc += sq[k] * W1[k * FDIM + f];
    sh[f] = siluf(acc);
    __syncthreads();
    float a0 = b2[f];
    float a1 = b2[FDIM + f];
    float a2 = b2[2 * FDIM + f];
#pragma unroll 4
    for (int k = 0; k < FDIM; k++) {
        float h = sh[k];
        const float* row = W2 + k * 3 * FDIM + f;
        a0 += h * row[0];
        a1 += h * row[FDIM];
        a2 += h * row[2 * FDIM];
    }
    float* xo = x + (size_t)a * (3 * FDIM);
    xo[f] = a0;
    xo[FDIM + f] = a1;
    xo[2 * FDIM + f] = a2;
}

// ---------------------------------------------------------------------------
// Edge message pass. One block (128 threads) per edge. Geometry (d, fcut,
// phi*fcut, dir) recomputed by threads 0..23 into LDS each layer.
// ---------------------------------------------------------------------------
__global__ __launch_bounds__(128) void edge_msg(
    const float* __restrict__ r3,
    const int* __restrict__ idx_i, const int* __restrict__ idx_j,
    const float* __restrict__ x, const float* __restrict__ mu,
    const float* __restrict__ fW, const float* __restrict__ fb, int layer,
    float* __restrict__ q, float* __restrict__ dmu) {
    int e = blockIdx.x;
    int f = threadIdx.x;
    __shared__ float se[24];
    if (f < 24) {
        float xx = r3[e * 3 + 0];
        float yy = r3[e * 3 + 1];
        float zz = r3[e * 3 + 2];
        float d = sqrtf(xx * xx + yy * yy + zz * zz);
        float val;
        if (f < 21) {
            float fc = (d < CUTOFF) ? 0.5f * (cosf(d * PI_F / CUTOFF) + 1.0f) : 0.0f;
            if (f < 20) {
                const float width = CUTOFF / (float)(NRBF - 1);
                const float coeff = -0.5f / (width * width);
                float t = d - width * (float)f;
                val = expf(coeff * t * t) * fc;
            } else {
                val = fc;
            }
        } else {
            float c = (f == 21) ? xx : (f == 22) ? yy : zz;
            val = c / d;
        }
        se[f] = val;
    }
    __syncthreads();
    int i = idx_i[e];
    int j = idx_j[e];
    int c0 = layer * 3 * FDIM + f;
    float fc = se[20];
    float f0 = fb[c0] * fc;
    float f1 = fb[c0 + FDIM] * fc;
    float f2 = fb[c0 + 2 * FDIM] * fc;
#pragma unroll
    for (int r = 0; r < NRBF; r++) {
        float p = se[r];
        const float* row = fW + r * (3 * 3 * FDIM) + c0;
        f0 += p * row[0];
        f1 += p * row[FDIM];
        f2 += p * row[2 * FDIM];
    }
    const float* xj = x + (size_t)j * (3 * FDIM);
    float dq    = f0 * xj[f];
    float dmuR  = f1 * xj[FDIM + f];
    float dmumu = f2 * xj[2 * FDIM + f];
    const float* muj = mu + (size_t)j * (3 * FDIM);
    float d0 = se[21], d1 = se[22], d2 = se[23];
    atomicAdd(q + (size_t)i * FDIM + f, dq);
    float* dmo = dmu + (size_t)i * (3 * FDIM);
    atomicAdd(dmo + f,            dmuR * d0 + dmumu * muj[f]);
    atomicAdd(dmo + FDIM + f,     dmuR * d1 + dmumu * muj[FDIM + f]);
    atomicAdd(dmo + 2 * FDIM + f, dmuR * d2 + dmumu * muj[2 * FDIM + f]);
}

// ---------------------------------------------------------------------------
// Fused per-atom update: mu += dmu; mix; norm; intra-MLP; q/mu updates.
// ---------------------------------------------------------------------------
__global__ __launch_bounds__(128) void atom_update(
    float* __restrict__ q, float* __restrict__ mu, const float* __restrict__ dmu,
    const float* __restrict__ mixW, const float* __restrict__ mixb,
    const float* __restrict__ iW1, const float* __restrict__ ib1,
    const float* __restrict__ iW2, const float* __restrict__ ib2) {
    int a = blockIdx.x;
    int f = threadIdx.x;
    __shared__ float smu[3 * FDIM];
    __shared__ float sctx[2 * FDIM];
    __shared__ float sh[FDIM];
    size_t mbase = (size_t)a * (3 * FDIM);
    float qa = q[(size_t)a * FDIM + f];
    float m0 = mu[mbase + f]            + dmu[mbase + f];
    float m1 = mu[mbase + FDIM + f]     + dmu[mbase + FDIM + f];
    float m2 = mu[mbase + 2 * FDIM + f] + dmu[mbase + 2 * FDIM + f];
    smu[f] = m0;
    smu[FDIM + f] = m1;
    smu[2 * FDIM + f] = m2;
    __syncthreads();
    float bV = mixb[f];
    float bW = mixb[FDIM + f];
    float v0 = bV, v1 = bV, v2 = bV;
    float w0 = bW, w1 = bW, w2 = bW;
#pragma unroll 4
    for (int k = 0; k < FDIM; k++) {
        float wv = mixW[k * 2 * FDIM + f];
        float ww = mixW[k * 2 * FDIM + FDIM + f];
        float u0 = smu[k], u1 = smu[FDIM + k], u2 = smu[2 * FDIM + k];
        v0 += u0 * wv; v1 += u1 * wv; v2 += u2 * wv;
        w0 += u0 * ww; w1 += u1 * ww; w2 += u2 * ww;
    }
    float vn = sqrtf(v0 * v0 + v1 * v1 + v2 * v2);
    sctx[f] = qa;
    sctx[FDIM + f] = vn;
    __syncthreads();
    float acc = ib1[f];
#pragma unroll 4
    for (int k = 0; k < 2 * FDIM; k++) acc += sctx[k] * iW1[k * FDIM + f];
    sh[f] = siluf(acc);
    __syncthreads();
    float x0 = ib2[f];
    float x1 = ib2[FDIM + f];
    float x2 = ib2[2 * FDIM + f];
#pragma unroll 4
    for (int k = 0; k < FDIM; k++) {
        float h = sh[k];
        const float* row = iW2 + k * 3 * FDIM + f;
        x0 += h * row[0];
        x1 += h * row[FDIM];
        x2 += h * row[2 * FDIM];
    }
    float s = v0 * w0 + v1 * w1 + v2 * w2;
    q[(size_t)a * FDIM + f] = qa + x0 + x2 * s;
    mu[mbase + f]            = m0 + x1 * w0;
    mu[mbase + FDIM + f]     = m1 + x1 * w1;
    mu[mbase + 2 * FDIM + f] = m2 + x1 * w2;
}

// ---------------------------------------------------------------------------
// Final write: q (N_ATOMS*F) then mu (N_ATOMS*3*F); dtype per flag.
// ---------------------------------------------------------------------------
__global__ void writeout(const float* __restrict__ q, const float* __restrict__ mu,
                         void* __restrict__ out, const int* __restrict__ flag) {
    int idx = blockIdx.x * blockDim.x + threadIdx.x;
    const int nq = N_ATOMS * FDIM;
    const int ntot = N_ATOMS * 4 * FDIM;
    if (idx >= ntot) return;
    float v = (idx < nq) ? q[idx] : mu[idx - nq];
    if (flag[0] != 0) ((bf16*)out)[idx] = __float2bfloat16(v);
    else              ((float*)out)[idx] = v;
}

extern "C" void kernel_launch(void* const* d_in, const int* in_sizes, int n_in,
                              void* d_out, int out_size, void* d_ws, size_t ws_size,
                              hipStream_t stream) {
    const int* zn    = (const int*)d_in[14];
    const int* idx_i = (const int*)d_in[15];
    const int* idx_j = (const int*)d_in[16];

    float* ws   = (float*)d_ws;
    int*   flag = (int*)d_ws;                       // 64-float pad
    float* fp   = ws + 64;                          // converted params
    float* q    = fp + P_TOTAL;                     // N_ATOMS*128
    float* mu   = q  + (size_t)N_ATOMS * FDIM;      // N_ATOMS*384
    float* dmu  = mu + (size_t)N_ATOMS * 3 * FDIM;  // N_ATOMS*384
    float* x    = dmu + (size_t)N_ATOMS * 3 * FDIM; // N_ATOMS*384

    detect_dtype<<<1, 256, 0, stream>>>(d_in[0], flag);

    CvtArgs ca;
    for (int t = 0; t < 14; t++) ca.src[t] = d_in[t];
    convert_all<<<(P_TOTAL + 255) / 256, 256, 0, stream>>>(ca, fp, flag);

    const float* r3  = fp + P_RIJ;
    const float* emb = fp + P_EMB;
    const float* fW  = fp + P_FW;
    const float* fb  = fp + P_FB;
    const float* iw1 = fp + P_IW1;
    const float* ib1 = fp + P_IB1;
    const float* iw2 = fp + P_IW2;
    const float* ib2 = fp + P_IB2;
    const float* mw  = fp + P_MW;
    const float* mb  = fp + P_MB;
    const float* aw1 = fp + P_AW1;
    const float* ab1 = fp + P_AB1;
    const float* aw2 = fp + P_AW2;
    const float* ab2 = fp + P_AB2;

    hipMemsetAsync(mu, 0, (size_t)N_ATOMS * 3 * FDIM * sizeof(float), stream);
    init_q<<<(N_ATOMS * FDIM + 255) / 256, 256, 0, stream>>>(zn, emb, q);

    for (int l = 0; l < 3; l++) {
        inter_mlp<<<N_ATOMS, 128, 0, stream>>>(
            q, iw1 + (size_t)l * FDIM * FDIM, ib1 + (size_t)l * FDIM,
            iw2 + (size_t)l * FDIM * 3 * FDIM, ib2 + (size_t)l * 3 * FDIM, x);
        hipMemsetAsync(dmu, 0, (size_t)N_ATOMS * 3 * FDIM * sizeof(float), stream);
        edge_msg<<<N_EDGES, 128, 0, stream>>>(
            r3, idx_i, idx_j, x, mu, fW, fb, l, q, dmu);
        atom_update<<<N_ATOMS, 128, 0, stream>>>(
            q, mu, dmu,
            mw + (size_t)l * FDIM * 2 * FDIM, mb + (size_t)l * 2 * FDIM,
            aw1 + (size_t)l * 2 * FDIM * FDIM, ab1 + (size_t)l * FDIM,
            aw2 + (size_t)l * FDIM * 3 * FDIM, ab2 + (size_t)l * 3 * FDIM);
    }

    int ntot = N_ATOMS * 4 * FDIM;
    writeout<<<(ntot + 255) / 256, 256, 0, stream>>>(q, mu, d_out, flag);
}

// Round 3
// 1513.134 us; speedup vs baseline: 1.7717x; 1.7717x over previous
//
#include <hip/hip_runtime.h>
#include <hip/hip_bf16.h>

#define N_ATOMS 15000
#define N_EDGES 300000
#define FDIM 128
#define NRBF 20
#define CUTOFF 5.0f
#define PI_F 3.14159265358979323846f

typedef __hip_bfloat16 bf16;

__device__ __forceinline__ float b2f(bf16 v) { return __bfloat162float(v); }
__device__ __forceinline__ float siluf(float x) { return x / (1.0f + __expf(-x)); }
__device__ __forceinline__ float lo_bf(unsigned u) { return __uint_as_float(u << 16); }
__device__ __forceinline__ float hi_bf(unsigned u) { return __uint_as_float(u & 0xffff0000u); }

// ---- converted-parameter offsets (f32 elements) -----------------------------
// order: r_ij, emb, fW, fb, iW1, ib1, iW2, ib2, mW, mb, aW1, ab1, aW2, ab2
__device__ __constant__ int c_off[15] = {
    0, 900000, 912800, 935840, 936992, 986144, 986528, 1133984,
    1135136, 1233440, 1234208, 1332512, 1332896, 1480352, 1481504};
#define P_TOTAL 1481504
#define P_RIJ 0
#define P_EMB 900000
#define P_FW  912800
#define P_FB  935840
#define P_IW1 936992
#define P_IB1 986144
#define P_IW2 986528
#define P_IB2 1133984
#define P_MW  1135136
#define P_MB  1233440
#define P_AW1 1234208
#define P_AB1 1332512
#define P_AW2 1332896
#define P_AB2 1480352

// ---------------------------------------------------------------------------
__global__ void detect_dtype(const void* __restrict__ r_ij, int* __restrict__ flag) {
    __shared__ int cnt;
    if (threadIdx.x == 0) cnt = 0;
    __syncthreads();
    const bf16* p = (const bf16*)r_ij;
    float v = fabsf(b2f(p[threadIdx.x]));
    int ok = (v > 0.0009765625f && v < 16.0f) ? 1 : 0;
    atomicAdd(&cnt, ok);
    __syncthreads();
    if (threadIdx.x == 0) flag[0] = (cnt > 204) ? 1 : 0;
}

struct CvtArgs { const void* src[14]; };

__global__ void convert_all(CvtArgs args, float* __restrict__ dst,
                            const int* __restrict__ flag) {
    int i = blockIdx.x * blockDim.x + threadIdx.x;
    if (i >= P_TOTAL) return;
    bool isbf = flag[0] != 0;
    int s = 0;
    while (i >= c_off[s + 1]) s++;
    int k = i - c_off[s];
    dst[i] = isbf ? b2f(((const bf16*)args.src[s])[k])
                  : ((const float*)args.src[s])[k];
}

// ---------------------------------------------------------------------------
__global__ void init_q(const int* __restrict__ zn, const float* __restrict__ emb,
                       float* __restrict__ q) {
    int idx = blockIdx.x * blockDim.x + threadIdx.x;
    if (idx >= N_ATOMS * FDIM) return;
    int a = idx >> 7;
    int f = idx & 127;
    q[idx] = emb[zn[a] * FDIM + f];
}

// ---------------------------------------------------------------------------
// Edge sort by idx_i: histogram -> exclusive scan -> scatter (with geometry).
// ---------------------------------------------------------------------------
__global__ void hist_kernel(const int* __restrict__ idx_i, int* __restrict__ counts) {
    int e = blockIdx.x * blockDim.x + threadIdx.x;
    if (e < N_EDGES) atomicAdd(&counts[idx_i[e]], 1);
}

__global__ void scan_kernel(const int* __restrict__ counts, int* __restrict__ start) {
    __shared__ int partial[256];
    int t = threadIdx.x;
    const int chunk = (N_ATOMS + 255) / 256;  // 59
    int base = t * chunk;
    int sum = 0;
    for (int k = 0; k < chunk; k++)
        if (base + k < N_ATOMS) sum += counts[base + k];
    partial[t] = sum;
    __syncthreads();
    for (int off = 1; off < 256; off <<= 1) {
        int v = (t >= off) ? partial[t - off] : 0;
        __syncthreads();
        partial[t] += v;
        __syncthreads();
    }
    int run = (t == 0) ? 0 : partial[t - 1];
    for (int k = 0; k < chunk; k++) {
        if (base + k < N_ATOMS) {
            start[base + k] = run;
            run += counts[base + k];
        }
    }
    if (t == 255) start[N_ATOMS] = run;
}

// Per edge: compute geometry (phi*fc x20, fc, dir x3 -> 24 bf16) and place at
// sorted position. sorted_j[pos] = idx_j.
__global__ void scatter_kernel(const float* __restrict__ r3,
                               const int* __restrict__ idx_i,
                               const int* __restrict__ idx_j,
                               const int* __restrict__ start,
                               int* __restrict__ cursor,
                               int* __restrict__ sorted_j,
                               bf16* __restrict__ edata) {
    int e = blockIdx.x * blockDim.x + threadIdx.x;
    if (e >= N_EDGES) return;
    float xx = r3[e * 3 + 0];
    float yy = r3[e * 3 + 1];
    float zz = r3[e * 3 + 2];
    float d = sqrtf(xx * xx + yy * yy + zz * zz);
    float inv = 1.0f / d;
    float fc = (d < CUTOFF) ? 0.5f * (cosf(d * PI_F / CUTOFF) + 1.0f) : 0.0f;
    const float width = CUTOFF / (float)(NRBF - 1);
    const float coeff = -0.5f / (width * width);
    int i = idx_i[e];
    int pos = start[i] + atomicAdd(&cursor[i], 1);
    sorted_j[pos] = idx_j[e];
    bf16* out = edata + (size_t)pos * 24;
#pragma unroll
    for (int r = 0; r < NRBF; r++) {
        float t = d - width * (float)r;
        out[r] = __float2bfloat16(__expf(coeff * t * t) * fc);
    }
    out[20] = __float2bfloat16(fc);
    out[21] = __float2bfloat16(xx * inv);
    out[22] = __float2bfloat16(yy * inv);
    out[23] = __float2bfloat16(zz * inv);
}

// ---------------------------------------------------------------------------
// Per-atom inter MLP: h = silu(q@W1+b1); x = h@W2+b2 -> bf16 table
// ---------------------------------------------------------------------------
__global__ __launch_bounds__(128) void inter_mlp(
    const float* __restrict__ q,
    const float* __restrict__ W1, const float* __restrict__ b1,
    const float* __restrict__ W2, const float* __restrict__ b2,
    bf16* __restrict__ xbf) {
    int a = blockIdx.x;
    int f = threadIdx.x;
    __shared__ float sq[FDIM];
    __shared__ float sh[FDIM];
    sq[f] = q[(size_t)a * FDIM + f];
    __syncthreads();
    float acc = b1[f];
#pragma unroll 4
    for (int k = 0; k < FDIM; k++) acc += sq[k] * W1[k * FDIM + f];
    sh[f] = siluf(acc);
    __syncthreads();
    float a0 = b2[f];
    float a1 = b2[FDIM + f];
    float a2 = b2[2 * FDIM + f];
#pragma unroll 4
    for (int k = 0; k < FDIM; k++) {
        float h = sh[k];
        const float* row = W2 + k * 3 * FDIM + f;
        a0 += h * row[0];
        a1 += h * row[FDIM];
        a2 += h * row[2 * FDIM];
    }
    bf16* xo = xbf + (size_t)a * (3 * FDIM);
    xo[f] = __float2bfloat16(a0);
    xo[FDIM + f] = __float2bfloat16(a1);
    xo[2 * FDIM + f] = __float2bfloat16(a2);
}

// ---------------------------------------------------------------------------
// Gather: one block (128 threads) per atom i. Filter weights (21 per output,
// fb folded in with basis fc) live in registers; per edge: 24 bf16 geometry
// broadcast, x[j]/mu[j] bf16 gathers, register accumulate. No atomics.
// ---------------------------------------------------------------------------
__global__ __launch_bounds__(128) void atom_gather(
    const int* __restrict__ start, const int* __restrict__ sorted_j,
    const bf16* __restrict__ edata,
    const bf16* __restrict__ xbf, const bf16* __restrict__ mubf,
    const float* __restrict__ fW, const float* __restrict__ fb, int layer,
    float* __restrict__ q, float* __restrict__ mu) {
    int a = blockIdx.x;
    int f = threadIdx.x;
    int c0 = layer * 3 * FDIM + f;
    float wq[21], wr[21], wm[21];
#pragma unroll
    for (int r = 0; r < NRBF; r++) {
        const float* row = fW + r * (9 * FDIM) + c0;
        wq[r] = row[0];
        wr[r] = row[FDIM];
        wm[r] = row[2 * FDIM];
    }
    wq[20] = fb[c0];
    wr[20] = fb[c0 + FDIM];
    wm[20] = fb[c0 + 2 * FDIM];

    float dq = 0.0f, dm0 = 0.0f, dm1 = 0.0f, dm2 = 0.0f;
    int s = start[a], e_end = start[a + 1];
    for (int pos = s; pos < e_end; pos++) {
        int j = sorted_j[pos];
        const uint4* edp = (const uint4*)(edata + (size_t)pos * 24);
        uint4 ua = edp[0];
        uint4 ub = edp[1];
        uint4 uc = edp[2];
        float se[24];
        se[0] = lo_bf(ua.x);  se[1] = hi_bf(ua.x);
        se[2] = lo_bf(ua.y);  se[3] = hi_bf(ua.y);
        se[4] = lo_bf(ua.z);  se[5] = hi_bf(ua.z);
        se[6] = lo_bf(ua.w);  se[7] = hi_bf(ua.w);
        se[8] = lo_bf(ub.x);  se[9] = hi_bf(ub.x);
        se[10] = lo_bf(ub.y); se[11] = hi_bf(ub.y);
        se[12] = lo_bf(ub.z); se[13] = hi_bf(ub.z);
        se[14] = lo_bf(ub.w); se[15] = hi_bf(ub.w);
        se[16] = lo_bf(uc.x); se[17] = hi_bf(uc.x);
        se[18] = lo_bf(uc.y); se[19] = hi_bf(uc.y);
        se[20] = lo_bf(uc.z); se[21] = hi_bf(uc.z);
        se[22] = lo_bf(uc.w); se[23] = hi_bf(uc.w);
        float f0 = 0.0f, f1 = 0.0f, f2 = 0.0f;
#pragma unroll
        for (int r = 0; r < 21; r++) {
            f0 += se[r] * wq[r];
            f1 += se[r] * wr[r];
            f2 += se[r] * wm[r];
        }
        size_t jb = (size_t)j * (3 * FDIM);
        float xj0 = b2f(xbf[jb + f]);
        float xj1 = b2f(xbf[jb + FDIM + f]);
        float xj2 = b2f(xbf[jb + 2 * FDIM + f]);
        float dmuR = f1 * xj1;
        float dmm = f2 * xj2;
        dq += f0 * xj0;
        dm0 += dmuR * se[21] + dmm * b2f(mubf[jb + f]);
        dm1 += dmuR * se[22] + dmm * b2f(mubf[jb + FDIM + f]);
        dm2 += dmuR * se[23] + dmm * b2f(mubf[jb + 2 * FDIM + f]);
    }
    q[(size_t)a * FDIM + f] += dq;
    size_t mbase = (size_t)a * (3 * FDIM);
    mu[mbase + f] += dm0;
    mu[mbase + FDIM + f] += dm1;
    mu[mbase + 2 * FDIM + f] += dm2;
}

// ---------------------------------------------------------------------------
// Per-atom update (mu master already includes edge dmu). Writes mu bf16 mirror.
// ---------------------------------------------------------------------------
__global__ __launch_bounds__(128) void atom_update(
    float* __restrict__ q, float* __restrict__ mu, bf16* __restrict__ mubf,
    const float* __restrict__ mixW, const float* __restrict__ mixb,
    const float* __restrict__ iW1, const float* __restrict__ ib1,
    const float* __restrict__ iW2, const float* __restrict__ ib2) {
    int a = blockIdx.x;
    int f = threadIdx.x;
    __shared__ float smu[3 * FDIM];
    __shared__ float sctx[2 * FDIM];
    __shared__ float sh[FDIM];
    size_t mbase = (size_t)a * (3 * FDIM);
    float qa = q[(size_t)a * FDIM + f];
    float m0 = mu[mbase + f];
    float m1 = mu[mbase + FDIM + f];
    float m2 = mu[mbase + 2 * FDIM + f];
    smu[f] = m0;
    smu[FDIM + f] = m1;
    smu[2 * FDIM + f] = m2;
    __syncthreads();
    float bV = mixb[f];
    float bW = mixb[FDIM + f];
    float v0 = bV, v1 = bV, v2 = bV;
    float w0 = bW, w1 = bW, w2 = bW;
#pragma unroll 4
    for (int k = 0; k < FDIM; k++) {
        float wv = mixW[k * 2 * FDIM + f];
        float ww = mixW[k * 2 * FDIM + FDIM + f];
        float u0 = smu[k], u1 = smu[FDIM + k], u2 = smu[2 * FDIM + k];
        v0 += u0 * wv; v1 += u1 * wv; v2 += u2 * wv;
        w0 += u0 * ww; w1 += u1 * ww; w2 += u2 * ww;
    }
    float vn = sqrtf(v0 * v0 + v1 * v1 + v2 * v2);
    sctx[f] = qa;
    sctx[FDIM + f] = vn;
    __syncthreads();
    float acc = ib1[f];
#pragma unroll 4
    for (int k = 0; k < 2 * FDIM; k++) acc += sctx[k] * iW1[k * FDIM + f];
    sh[f] = siluf(acc);
    __syncthreads();
    float x0 = ib2[f];
    float x1 = ib2[FDIM + f];
    float x2 = ib2[2 * FDIM + f];
#pragma unroll 4
    for (int k = 0; k < FDIM; k++) {
        float h = sh[k];
        const float* row = iW2 + k * 3 * FDIM + f;
        x0 += h * row[0];
        x1 += h * row[FDIM];
        x2 += h * row[2 * FDIM];
    }
    float s = v0 * w0 + v1 * w1 + v2 * w2;
    q[(size_t)a * FDIM + f] = qa + x0 + x2 * s;
    float n0 = m0 + x1 * w0;
    float n1 = m1 + x1 * w1;
    float n2 = m2 + x1 * w2;
    mu[mbase + f] = n0;
    mu[mbase + FDIM + f] = n1;
    mu[mbase + 2 * FDIM + f] = n2;
    mubf[mbase + f] = __float2bfloat16(n0);
    mubf[mbase + FDIM + f] = __float2bfloat16(n1);
    mubf[mbase + 2 * FDIM + f] = __float2bfloat16(n2);
}

// ---------------------------------------------------------------------------
__global__ void writeout(const float* __restrict__ q, const float* __restrict__ mu,
                         void* __restrict__ out, const int* __restrict__ flag) {
    int idx = blockIdx.x * blockDim.x + threadIdx.x;
    const int nq = N_ATOMS * FDIM;
    const int ntot = N_ATOMS * 4 * FDIM;
    if (idx >= ntot) return;
    float v = (idx < nq) ? q[idx] : mu[idx - nq];
    if (flag[0] != 0) ((bf16*)out)[idx] = __float2bfloat16(v);
    else              ((float*)out)[idx] = v;
}

extern "C" void kernel_launch(void* const* d_in, const int* in_sizes, int n_in,
                              void* d_out, int out_size, void* d_ws, size_t ws_size,
                              hipStream_t stream) {
    const int* zn    = (const int*)d_in[14];
    const int* idx_i = (const int*)d_in[15];
    const int* idx_j = (const int*)d_in[16];

    char* base = (char*)d_ws;
    int*   flag     = (int*)base;                                  // 256 B
    float* fp       = (float*)(base + 256);                        // 5,926,016 B
    float* q        = (float*)(base + 256 + 5926016);              // 7,680,000
    float* mu       = (float*)(base + 256 + 5926016 + 7680000);    // 23,040,000
    bf16*  xbf      = (bf16*)(base + 36646272);                    // 11,520,000
    bf16*  mubf     = (bf16*)(base + 48166272);                    // 11,520,000
    int*   counts   = (int*)(base + 59686272);                     // 60,032
    int*   cursor   = (int*)(base + 59746304);                     // 60,032
    int*   startarr = (int*)(base + 59806336);                     // 60,032
    int*   sorted_j = (int*)(base + 59866368);                     // 1,200,000
    bf16*  edata    = (bf16*)(base + 61066368);                    // 14,400,000 -> 75.5 MB

    detect_dtype<<<1, 256, 0, stream>>>(d_in[0], flag);

    CvtArgs ca;
    for (int t = 0; t < 14; t++) ca.src[t] = d_in[t];
    convert_all<<<(P_TOTAL + 255) / 256, 256, 0, stream>>>(ca, fp, flag);

    const float* r3  = fp + P_RIJ;
    const float* emb = fp + P_EMB;
    const float* fW  = fp + P_FW;
    const float* fb  = fp + P_FB;
    const float* iw1 = fp + P_IW1;
    const float* ib1 = fp + P_IB1;
    const float* iw2 = fp + P_IW2;
    const float* ib2 = fp + P_IB2;
    const float* mw  = fp + P_MW;
    const float* mb  = fp + P_MB;
    const float* aw1 = fp + P_AW1;
    const float* ab1 = fp + P_AB1;
    const float* aw2 = fp + P_AW2;
    const float* ab2 = fp + P_AB2;

    // sort edges by destination atom
    hipMemsetAsync(counts, 0, 2 * 60032, stream);  // counts + cursor
    hist_kernel<<<(N_EDGES + 255) / 256, 256, 0, stream>>>(idx_i, counts);
    scan_kernel<<<1, 256, 0, stream>>>(counts, startarr);
    scatter_kernel<<<(N_EDGES + 255) / 256, 256, 0, stream>>>(
        r3, idx_i, idx_j, startarr, cursor, sorted_j, edata);

    hipMemsetAsync(mu, 0, (size_t)N_ATOMS * 3 * FDIM * sizeof(float), stream);
    hipMemsetAsync(mubf, 0, (size_t)N_ATOMS * 3 * FDIM * sizeof(bf16), stream);
    init_q<<<(N_ATOMS * FDIM + 255) / 256, 256, 0, stream>>>(zn, emb, q);

    for (int l = 0; l < 3; l++) {
        inter_mlp<<<N_ATOMS, 128, 0, stream>>>(
            q, iw1 + (size_t)l * FDIM * FDIM, ib1 + (size_t)l * FDIM,
            iw2 + (size_t)l * FDIM * 3 * FDIM, ib2 + (size_t)l * 3 * FDIM, xbf);
        atom_gather<<<N_ATOMS, 128, 0, stream>>>(
            startarr, sorted_j, edata, xbf, mubf, fW, fb, l, q, mu);
        atom_update<<<N_ATOMS, 128, 0, stream>>>(
            q, mu, mubf,
            mw + (size_t)l * FDIM * 2 * FDIM, mb + (size_t)l * 2 * FDIM,
            aw1 + (size_t)l * 2 * FDIM * FDIM, ab1 + (size_t)l * FDIM,
            aw2 + (size_t)l * FDIM * 3 * FDIM, ab2 + (size_t)l * 3 * FDIM);
    }

    int ntot = N_ATOMS * 4 * FDIM;
    writeout<<<(ntot + 255) / 256, 256, 0, stream>>>(q, mu, d_out, flag);
}

// Round 4
// 1139.910 us; speedup vs baseline: 2.3518x; 1.3274x over previous
//
#include <hip/hip_runtime.h>
#include <hip/hip_bf16.h>

#define N_ATOMS 15000
#define N_EDGES 300000
#define FDIM 128
#define NRBF 20
#define CUTOFF 5.0f
#define PI_F 3.14159265358979323846f
#define AB 8   // atoms per block in MLP kernels

typedef __hip_bfloat16 bf16;

__device__ __forceinline__ float b2f(bf16 v) { return __bfloat162float(v); }
__device__ __forceinline__ float siluf(float x) { return x / (1.0f + __expf(-x)); }
__device__ __forceinline__ float lo_bf(unsigned u) { return __uint_as_float(u << 16); }
__device__ __forceinline__ float hi_bf(unsigned u) { return __uint_as_float(u & 0xffff0000u); }

// ---- converted-parameter offsets (f32 elements) -----------------------------
__device__ __constant__ int c_off[15] = {
    0, 900000, 912800, 935840, 936992, 986144, 986528, 1133984,
    1135136, 1233440, 1234208, 1332512, 1332896, 1480352, 1481504};
#define P_TOTAL 1481504
#define P_RIJ 0
#define P_EMB 900000
#define P_FW  912800
#define P_FB  935840
#define P_IW1 936992
#define P_IB1 986144
#define P_IW2 986528
#define P_IB2 1133984
#define P_MW  1135136
#define P_MB  1233440
#define P_AW1 1234208
#define P_AB1 1332512
#define P_AW2 1332896
#define P_AB2 1480352

// ---------------------------------------------------------------------------
__global__ void detect_dtype(const void* __restrict__ r_ij, int* __restrict__ flag) {
    __shared__ int cnt;
    if (threadIdx.x == 0) cnt = 0;
    __syncthreads();
    const bf16* p = (const bf16*)r_ij;
    float v = fabsf(b2f(p[threadIdx.x]));
    int ok = (v > 0.0009765625f && v < 16.0f) ? 1 : 0;
    atomicAdd(&cnt, ok);
    __syncthreads();
    if (threadIdx.x == 0) flag[0] = (cnt > 204) ? 1 : 0;
}

struct CvtArgs { const void* src[14]; };

__global__ void convert_all(CvtArgs args, float* __restrict__ dst,
                            const int* __restrict__ flag) {
    int i = blockIdx.x * blockDim.x + threadIdx.x;
    if (i >= P_TOTAL) return;
    bool isbf = flag[0] != 0;
    int s = 0;
    while (i >= c_off[s + 1]) s++;
    int k = i - c_off[s];
    dst[i] = isbf ? b2f(((const bf16*)args.src[s])[k])
                  : ((const float*)args.src[s])[k];
}

// ---------------------------------------------------------------------------
__global__ void init_q(const int* __restrict__ zn, const float* __restrict__ emb,
                       float* __restrict__ q) {
    int idx = blockIdx.x * blockDim.x + threadIdx.x;
    if (idx >= N_ATOMS * FDIM) return;
    int a = idx >> 7;
    int f = idx & 127;
    q[idx] = emb[zn[a] * FDIM + f];
}

// ---------------------------------------------------------------------------
// Edge sort by idx_i
// ---------------------------------------------------------------------------
__global__ void hist_kernel(const int* __restrict__ idx_i, int* __restrict__ counts) {
    int e = blockIdx.x * blockDim.x + threadIdx.x;
    if (e < N_EDGES) atomicAdd(&counts[idx_i[e]], 1);
}

__global__ void scan_kernel(const int* __restrict__ counts, int* __restrict__ start) {
    __shared__ int partial[256];
    int t = threadIdx.x;
    const int chunk = (N_ATOMS + 255) / 256;
    int base = t * chunk;
    int sum = 0;
    for (int k = 0; k < chunk; k++)
        if (base + k < N_ATOMS) sum += counts[base + k];
    partial[t] = sum;
    __syncthreads();
    for (int off = 1; off < 256; off <<= 1) {
        int v = (t >= off) ? partial[t - off] : 0;
        __syncthreads();
        partial[t] += v;
        __syncthreads();
    }
    int run = (t == 0) ? 0 : partial[t - 1];
    for (int k = 0; k < chunk; k++) {
        if (base + k < N_ATOMS) {
            start[base + k] = run;
            run += counts[base + k];
        }
    }
    if (t == 255) start[N_ATOMS] = run;
}

__global__ void scatter_kernel(const float* __restrict__ r3,
                               const int* __restrict__ idx_i,
                               const int* __restrict__ idx_j,
                               const int* __restrict__ start,
                               int* __restrict__ cursor,
                               int* __restrict__ sorted_j,
                               bf16* __restrict__ edata) {
    int e = blockIdx.x * blockDim.x + threadIdx.x;
    if (e >= N_EDGES) return;
    float xx = r3[e * 3 + 0];
    float yy = r3[e * 3 + 1];
    float zz = r3[e * 3 + 2];
    float d = sqrtf(xx * xx + yy * yy + zz * zz);
    float inv = 1.0f / d;
    float fc = (d < CUTOFF) ? 0.5f * (cosf(d * PI_F / CUTOFF) + 1.0f) : 0.0f;
    const float width = CUTOFF / (float)(NRBF - 1);
    const float coeff = -0.5f / (width * width);
    int i = idx_i[e];
    int pos = start[i] + atomicAdd(&cursor[i], 1);
    sorted_j[pos] = idx_j[e];
    bf16* out = edata + (size_t)pos * 24;
#pragma unroll
    for (int r = 0; r < NRBF; r++) {
        float t = d - width * (float)r;
        out[r] = __float2bfloat16(__expf(coeff * t * t) * fc);
    }
    out[20] = __float2bfloat16(fc);
    out[21] = __float2bfloat16(xx * inv);
    out[22] = __float2bfloat16(yy * inv);
    out[23] = __float2bfloat16(zz * inv);
}

// ---------------------------------------------------------------------------
// Inter MLP, AB atoms per block: h = silu(q@W1+b1); x = h@W2+b2 -> bf16 table
// ---------------------------------------------------------------------------
__global__ __launch_bounds__(128) void inter_mlp(
    const float* __restrict__ q,
    const float* __restrict__ W1, const float* __restrict__ b1,
    const float* __restrict__ W2, const float* __restrict__ b2,
    bf16* __restrict__ xbf) {
    int a0 = blockIdx.x * AB;
    int f = threadIdx.x;
    __shared__ float sq[AB * FDIM];
    __shared__ float sh[AB * FDIM];
    for (int idx = f; idx < AB * FDIM; idx += 128)
        sq[idx] = q[(size_t)a0 * FDIM + idx];
    __syncthreads();
    float acc[AB];
    float bb = b1[f];
#pragma unroll
    for (int a = 0; a < AB; a++) acc[a] = bb;
    for (int k = 0; k < FDIM; k++) {
        float w = W1[k * FDIM + f];
#pragma unroll
        for (int a = 0; a < AB; a++) acc[a] += sq[a * FDIM + k] * w;
    }
#pragma unroll
    for (int a = 0; a < AB; a++) sh[a * FDIM + f] = siluf(acc[a]);
    __syncthreads();
    float x0[AB], x1[AB], x2[AB];
    float c0 = b2[f], c1 = b2[FDIM + f], c2 = b2[2 * FDIM + f];
#pragma unroll
    for (int a = 0; a < AB; a++) { x0[a] = c0; x1[a] = c1; x2[a] = c2; }
    for (int k = 0; k < FDIM; k++) {
        const float* row = W2 + k * 3 * FDIM + f;
        float r0 = row[0], r1 = row[FDIM], r2 = row[2 * FDIM];
#pragma unroll
        for (int a = 0; a < AB; a++) {
            float h = sh[a * FDIM + k];
            x0[a] += h * r0; x1[a] += h * r1; x2[a] += h * r2;
        }
    }
#pragma unroll
    for (int a = 0; a < AB; a++) {
        bf16* xo = xbf + ((size_t)(a0 + a)) * (3 * FDIM);
        xo[f] = __float2bfloat16(x0[a]);
        xo[FDIM + f] = __float2bfloat16(x1[a]);
        xo[2 * FDIM + f] = __float2bfloat16(x2[a]);
    }
}

// ---------------------------------------------------------------------------
// Gather: one block (128 threads) per atom i. No atomics.
// ---------------------------------------------------------------------------
__global__ __launch_bounds__(128) void atom_gather(
    const int* __restrict__ start, const int* __restrict__ sorted_j,
    const bf16* __restrict__ edata,
    const bf16* __restrict__ xbf, const bf16* __restrict__ mubf,
    const float* __restrict__ fW, const float* __restrict__ fb, int layer,
    float* __restrict__ q, float* __restrict__ mu) {
    int a = blockIdx.x;
    int f = threadIdx.x;
    int c0 = layer * 3 * FDIM + f;
    float wq[21], wr[21], wm[21];
#pragma unroll
    for (int r = 0; r < NRBF; r++) {
        const float* row = fW + r * (9 * FDIM) + c0;
        wq[r] = row[0];
        wr[r] = row[FDIM];
        wm[r] = row[2 * FDIM];
    }
    wq[20] = fb[c0];
    wr[20] = fb[c0 + FDIM];
    wm[20] = fb[c0 + 2 * FDIM];

    float dq = 0.0f, dm0 = 0.0f, dm1 = 0.0f, dm2 = 0.0f;
    int s = start[a], e_end = start[a + 1];
    for (int pos = s; pos < e_end; pos++) {
        int j = sorted_j[pos];
        const uint4* edp = (const uint4*)(edata + (size_t)pos * 24);
        uint4 ua = edp[0];
        uint4 ub = edp[1];
        uint4 uc = edp[2];
        float se[24];
        se[0] = lo_bf(ua.x);  se[1] = hi_bf(ua.x);
        se[2] = lo_bf(ua.y);  se[3] = hi_bf(ua.y);
        se[4] = lo_bf(ua.z);  se[5] = hi_bf(ua.z);
        se[6] = lo_bf(ua.w);  se[7] = hi_bf(ua.w);
        se[8] = lo_bf(ub.x);  se[9] = hi_bf(ub.x);
        se[10] = lo_bf(ub.y); se[11] = hi_bf(ub.y);
        se[12] = lo_bf(ub.z); se[13] = hi_bf(ub.z);
        se[14] = lo_bf(ub.w); se[15] = hi_bf(ub.w);
        se[16] = lo_bf(uc.x); se[17] = hi_bf(uc.x);
        se[18] = lo_bf(uc.y); se[19] = hi_bf(uc.y);
        se[20] = lo_bf(uc.z); se[21] = hi_bf(uc.z);
        se[22] = lo_bf(uc.w); se[23] = hi_bf(uc.w);
        float f0 = 0.0f, f1 = 0.0f, f2 = 0.0f;
#pragma unroll
        for (int r = 0; r < 21; r++) {
            f0 += se[r] * wq[r];
            f1 += se[r] * wr[r];
            f2 += se[r] * wm[r];
        }
        size_t jb = (size_t)j * (3 * FDIM);
        float xj0 = b2f(xbf[jb + f]);
        float xj1 = b2f(xbf[jb + FDIM + f]);
        float xj2 = b2f(xbf[jb + 2 * FDIM + f]);
        float dmuR = f1 * xj1;
        float dmm = f2 * xj2;
        dq += f0 * xj0;
        dm0 += dmuR * se[21] + dmm * b2f(mubf[jb + f]);
        dm1 += dmuR * se[22] + dmm * b2f(mubf[jb + FDIM + f]);
        dm2 += dmuR * se[23] + dmm * b2f(mubf[jb + 2 * FDIM + f]);
    }
    q[(size_t)a * FDIM + f] += dq;
    size_t mbase = (size_t)a * (3 * FDIM);
    mu[mbase + f] += dm0;
    mu[mbase + FDIM + f] += dm1;
    mu[mbase + 2 * FDIM + f] += dm2;
}

// ---------------------------------------------------------------------------
// Per-atom update, AB atoms per block.
// ---------------------------------------------------------------------------
__global__ __launch_bounds__(128) void atom_update(
    float* __restrict__ q, float* __restrict__ mu, bf16* __restrict__ mubf,
    const float* __restrict__ mixW, const float* __restrict__ mixb,
    const float* __restrict__ iW1, const float* __restrict__ ib1,
    const float* __restrict__ iW2, const float* __restrict__ ib2) {
    int a0 = blockIdx.x * AB;
    int f = threadIdx.x;
    __shared__ float smu[AB * 3 * FDIM];   // 12 KB
    __shared__ float sq[AB * FDIM];        // 4 KB
    __shared__ float sctx[AB * 2 * FDIM];  // 8 KB
    __shared__ float sh[AB * FDIM];        // 4 KB
    for (int idx = f; idx < AB * 3 * FDIM; idx += 128)
        smu[idx] = mu[(size_t)a0 * 3 * FDIM + idx];
    for (int idx = f; idx < AB * FDIM; idx += 128)
        sq[idx] = q[(size_t)a0 * FDIM + idx];
    __syncthreads();
    // mix: V = mu@mixW[:, :128], W = mu@mixW[:, 128:]
    float v0[AB], v1[AB], v2[AB], w0[AB], w1[AB], w2[AB];
    float bV = mixb[f], bW = mixb[FDIM + f];
#pragma unroll
    for (int a = 0; a < AB; a++) {
        v0[a] = bV; v1[a] = bV; v2[a] = bV;
        w0[a] = bW; w1[a] = bW; w2[a] = bW;
    }
    for (int k = 0; k < FDIM; k++) {
        float wv = mixW[k * 2 * FDIM + f];
        float ww = mixW[k * 2 * FDIM + FDIM + f];
#pragma unroll
        for (int a = 0; a < AB; a++) {
            float u0 = smu[a * 3 * FDIM + k];
            float u1 = smu[a * 3 * FDIM + FDIM + k];
            float u2 = smu[a * 3 * FDIM + 2 * FDIM + k];
            v0[a] += u0 * wv; v1[a] += u1 * wv; v2[a] += u2 * wv;
            w0[a] += u0 * ww; w1[a] += u1 * ww; w2[a] += u2 * ww;
        }
    }
    float sdot[AB];
#pragma unroll
    for (int a = 0; a < AB; a++) {
        sdot[a] = v0[a] * w0[a] + v1[a] * w1[a] + v2[a] * w2[a];
        float vn = sqrtf(v0[a] * v0[a] + v1[a] * v1[a] + v2[a] * v2[a]);
        sctx[a * 2 * FDIM + f] = sq[a * FDIM + f];
        sctx[a * 2 * FDIM + FDIM + f] = vn;
    }
    __syncthreads();
    float acc[AB];
    float bi = ib1[f];
#pragma unroll
    for (int a = 0; a < AB; a++) acc[a] = bi;
    for (int k = 0; k < 2 * FDIM; k++) {
        float w = iW1[k * FDIM + f];
#pragma unroll
        for (int a = 0; a < AB; a++) acc[a] += sctx[a * 2 * FDIM + k] * w;
    }
#pragma unroll
    for (int a = 0; a < AB; a++) sh[a * FDIM + f] = siluf(acc[a]);
    __syncthreads();
    float x0[AB], x1[AB], x2[AB];
    float c0 = ib2[f], c1 = ib2[FDIM + f], c2 = ib2[2 * FDIM + f];
#pragma unroll
    for (int a = 0; a < AB; a++) { x0[a] = c0; x1[a] = c1; x2[a] = c2; }
    for (int k = 0; k < FDIM; k++) {
        const float* row = iW2 + k * 3 * FDIM + f;
        float r0 = row[0], r1 = row[FDIM], r2 = row[2 * FDIM];
#pragma unroll
        for (int a = 0; a < AB; a++) {
            float h = sh[a * FDIM + k];
            x0[a] += h * r0; x1[a] += h * r1; x2[a] += h * r2;
        }
    }
#pragma unroll
    for (int a = 0; a < AB; a++) {
        size_t mbase = ((size_t)(a0 + a)) * 3 * FDIM;
        q[((size_t)(a0 + a)) * FDIM + f] = sq[a * FDIM + f] + x0[a] + x2[a] * sdot[a];
        float n0 = smu[a * 3 * FDIM + f] + x1[a] * w0[a];
        float n1 = smu[a * 3 * FDIM + FDIM + f] + x1[a] * w1[a];
        float n2 = smu[a * 3 * FDIM + 2 * FDIM + f] + x1[a] * w2[a];
        mu[mbase + f] = n0;
        mu[mbase + FDIM + f] = n1;
        mu[mbase + 2 * FDIM + f] = n2;
        mubf[mbase + f] = __float2bfloat16(n0);
        mubf[mbase + FDIM + f] = __float2bfloat16(n1);
        mubf[mbase + 2 * FDIM + f] = __float2bfloat16(n2);
    }
}

// ---------------------------------------------------------------------------
__global__ void writeout(const float* __restrict__ q, const float* __restrict__ mu,
                         void* __restrict__ out, const int* __restrict__ flag) {
    int idx = blockIdx.x * blockDim.x + threadIdx.x;
    const int nq = N_ATOMS * FDIM;
    const int ntot = N_ATOMS * 4 * FDIM;
    if (idx >= ntot) return;
    float v = (idx < nq) ? q[idx] : mu[idx - nq];
    if (flag[0] != 0) ((bf16*)out)[idx] = __float2bfloat16(v);
    else              ((float*)out)[idx] = v;
}

extern "C" void kernel_launch(void* const* d_in, const int* in_sizes, int n_in,
                              void* d_out, int out_size, void* d_ws, size_t ws_size,
                              hipStream_t stream) {
    const int* zn    = (const int*)d_in[14];
    const int* idx_i = (const int*)d_in[15];
    const int* idx_j = (const int*)d_in[16];

    char* base = (char*)d_ws;
    int*   flag     = (int*)base;
    float* fp       = (float*)(base + 256);
    float* q        = (float*)(base + 256 + 5926016);
    float* mu       = (float*)(base + 256 + 5926016 + 7680000);
    bf16*  xbf      = (bf16*)(base + 36646272);
    bf16*  mubf     = (bf16*)(base + 48166272);
    int*   counts   = (int*)(base + 59686272);
    int*   cursor   = (int*)(base + 59746304);
    int*   startarr = (int*)(base + 59806336);
    int*   sorted_j = (int*)(base + 59866368);
    bf16*  edata    = (bf16*)(base + 61066368);   // ends at ~75.5 MB

    detect_dtype<<<1, 256, 0, stream>>>(d_in[0], flag);

    CvtArgs ca;
    for (int t = 0; t < 14; t++) ca.src[t] = d_in[t];
    convert_all<<<(P_TOTAL + 255) / 256, 256, 0, stream>>>(ca, fp, flag);

    const float* r3  = fp + P_RIJ;
    const float* emb = fp + P_EMB;
    const float* fW  = fp + P_FW;
    const float* fb  = fp + P_FB;
    const float* iw1 = fp + P_IW1;
    const float* ib1 = fp + P_IB1;
    const float* iw2 = fp + P_IW2;
    const float* ib2 = fp + P_IB2;
    const float* mw  = fp + P_MW;
    const float* mb  = fp + P_MB;
    const float* aw1 = fp + P_AW1;
    const float* ab1 = fp + P_AB1;
    const float* aw2 = fp + P_AW2;
    const float* ab2 = fp + P_AB2;

    hipMemsetAsync(counts, 0, 2 * 60032, stream);
    hist_kernel<<<(N_EDGES + 255) / 256, 256, 0, stream>>>(idx_i, counts);
    scan_kernel<<<1, 256, 0, stream>>>(counts, startarr);
    scatter_kernel<<<(N_EDGES + 255) / 256, 256, 0, stream>>>(
        r3, idx_i, idx_j, startarr, cursor, sorted_j, edata);

    hipMemsetAsync(mu, 0, (size_t)N_ATOMS * 3 * FDIM * sizeof(float), stream);
    hipMemsetAsync(mubf, 0, (size_t)N_ATOMS * 3 * FDIM * sizeof(bf16), stream);
    init_q<<<(N_ATOMS * FDIM + 255) / 256, 256, 0, stream>>>(zn, emb, q);

    const int nblk = (N_ATOMS + AB - 1) / AB;  // 1875
    for (int l = 0; l < 3; l++) {
        inter_mlp<<<nblk, 128, 0, stream>>>(
            q, iw1 + (size_t)l * FDIM * FDIM, ib1 + (size_t)l * FDIM,
            iw2 + (size_t)l * FDIM * 3 * FDIM, ib2 + (size_t)l * 3 * FDIM, xbf);
        atom_gather<<<N_ATOMS, 128, 0, stream>>>(
            startarr, sorted_j, edata, xbf, mubf, fW, fb, l, q, mu);
        atom_update<<<nblk, 128, 0, stream>>>(
            q, mu, mubf,
            mw + (size_t)l * FDIM * 2 * FDIM, mb + (size_t)l * 2 * FDIM,
            aw1 + (size_t)l * 2 * FDIM * FDIM, ab1 + (size_t)l * FDIM,
            aw2 + (size_t)l * FDIM * 3 * FDIM, ab2 + (size_t)l * 3 * FDIM);
    }

    int ntot = N_ATOMS * 4 * FDIM;
    writeout<<<(ntot + 255) / 256, 256, 0, stream>>>(q, mu, d_out, flag);
}

// Round 5
// 690.664 us; speedup vs baseline: 3.8815x; 1.6505x over previous
//
#include <hip/hip_runtime.h>
#include <hip/hip_bf16.h>

#define N_ATOMS 15000
#define N_EDGES 300000
#define FDIM 128
#define NRBF 20
#define CUTOFF 5.0f
#define PI_F 3.14159265358979323846f
#define MT 16            // atoms per MFMA block
#define NBLK 938         // ceil(15000/16)

typedef __hip_bfloat16 bf16;
using bf16x8 = __attribute__((ext_vector_type(8))) short;  // 8 bf16 (4 VGPRs)
using f32x4  = __attribute__((ext_vector_type(4))) float;  // 4 f32 acc

#define MFMA(a, b, c) __builtin_amdgcn_mfma_f32_16x16x32_bf16(a, b, c, 0, 0, 0)

__device__ __forceinline__ float b2f(bf16 v) { return __bfloat162float(v); }
__device__ __forceinline__ float siluf(float x) { return x / (1.0f + __expf(-x)); }
__device__ __forceinline__ float lo_bf(unsigned u) { return __uint_as_float(u << 16); }
__device__ __forceinline__ float hi_bf(unsigned u) { return __uint_as_float(u & 0xffff0000u); }

// ---- converted-parameter offsets (f32 elements) -----------------------------
__device__ __constant__ int c_off[15] = {
    0, 900000, 912800, 935840, 936992, 986144, 986528, 1133984,
    1135136, 1233440, 1234208, 1332512, 1332896, 1480352, 1481504};
#define P_TOTAL 1481504
#define P_RIJ 0
#define P_EMB 900000
#define P_FW  912800
#define P_FB  935840
#define P_IW1 936992
#define P_IB1 986144
#define P_IW2 986528
#define P_IB2 1133984
#define P_MW  1135136
#define P_MB  1233440
#define P_AW1 1234208
#define P_AB1 1332512
#define P_AW2 1332896
#define P_AB2 1480352

// packed-weight (bf16) layout: per layer 180224 elems:
//   iW1 @0 (128x128), iW2 @16384 (128x384), mW @65536 (128x256),
//   aW1 @98304 (256x128), aW2 @131072 (128x384)
#define WPACK_L 180224

// ---------------------------------------------------------------------------
__global__ void detect_dtype(const void* __restrict__ r_ij, int* __restrict__ flag) {
    __shared__ int cnt;
    if (threadIdx.x == 0) cnt = 0;
    __syncthreads();
    const bf16* p = (const bf16*)r_ij;
    float v = fabsf(b2f(p[threadIdx.x]));
    int ok = (v > 0.0009765625f && v < 16.0f) ? 1 : 0;
    atomicAdd(&cnt, ok);
    __syncthreads();
    if (threadIdx.x == 0) flag[0] = (cnt > 204) ? 1 : 0;
}

struct CvtArgs { const void* src[14]; };

__global__ void convert_all(CvtArgs args, float* __restrict__ dst,
                            const int* __restrict__ flag) {
    int i = blockIdx.x * blockDim.x + threadIdx.x;
    if (i >= P_TOTAL) return;
    bool isbf = flag[0] != 0;
    int s = 0;
    while (i >= c_off[s + 1]) s++;
    int k = i - c_off[s];
    dst[i] = isbf ? b2f(((const bf16*)args.src[s])[k])
                  : ((const float*)args.src[s])[k];
}

// ---------------------------------------------------------------------------
// Pack 5 weight matrices x 3 layers into MFMA-B fragment order:
// dst[((k>>5)*4 + ((k>>3)&3))*N*8 + n*8 + (k&7)]
// ---------------------------------------------------------------------------
__global__ void pack_w(const float* __restrict__ fp, bf16* __restrict__ wbf) {
    int i = blockIdx.x * blockDim.x + threadIdx.x;
    if (i >= 3 * WPACK_L) return;
    int l = i / WPACK_L;
    int r = i - l * WPACK_L;
    int m, off;
    if (r < 16384)       { m = 0; off = r; }
    else if (r < 65536)  { m = 1; off = r - 16384; }
    else if (r < 98304)  { m = 2; off = r - 65536; }
    else if (r < 131072) { m = 3; off = r - 98304; }
    else                 { m = 4; off = r - 131072; }
    const int pkN[5] = {128, 384, 256, 128, 384};
    const int pkD[5] = {0, 16384, 65536, 98304, 131072};
    int N = pkN[m];
    int k = off / N;
    int n = off - k * N;
    int srcb;
    switch (m) {
        case 0: srcb = P_IW1 + l * 16384; break;
        case 1: srcb = P_IW2 + l * 49152; break;
        case 2: srcb = P_MW  + l * 32768; break;
        case 3: srcb = P_AW1 + l * 32768; break;
        default: srcb = P_AW2 + l * 49152; break;
    }
    float v = fp[srcb + off];
    int dst = l * WPACK_L + pkD[m] +
              (((k >> 5) * 4 + ((k >> 3) & 3)) * N + n) * 8 + (k & 7);
    wbf[dst] = __float2bfloat16(v);
}

// ---------------------------------------------------------------------------
__global__ void init_q(const int* __restrict__ zn, const float* __restrict__ emb,
                       float* __restrict__ q) {
    int idx = blockIdx.x * blockDim.x + threadIdx.x;
    if (idx >= N_ATOMS * FDIM) return;
    int a = idx >> 7;
    int f = idx & 127;
    q[idx] = emb[zn[a] * FDIM + f];
}

// ---------------------------------------------------------------------------
// Edge sort by idx_i
// ---------------------------------------------------------------------------
__global__ void hist_kernel(const int* __restrict__ idx_i, int* __restrict__ counts) {
    int e = blockIdx.x * blockDim.x + threadIdx.x;
    if (e < N_EDGES) atomicAdd(&counts[idx_i[e]], 1);
}

__global__ void scan_kernel(const int* __restrict__ counts, int* __restrict__ start) {
    __shared__ int partial[256];
    int t = threadIdx.x;
    const int chunk = (N_ATOMS + 255) / 256;
    int base = t * chunk;
    int sum = 0;
    for (int k = 0; k < chunk; k++)
        if (base + k < N_ATOMS) sum += counts[base + k];
    partial[t] = sum;
    __syncthreads();
    for (int off = 1; off < 256; off <<= 1) {
        int v = (t >= off) ? partial[t - off] : 0;
        __syncthreads();
        partial[t] += v;
        __syncthreads();
    }
    int run = (t == 0) ? 0 : partial[t - 1];
    for (int k = 0; k < chunk; k++) {
        if (base + k < N_ATOMS) {
            start[base + k] = run;
            run += counts[base + k];
        }
    }
    if (t == 255) start[N_ATOMS] = run;
}

__global__ void scatter_kernel(const float* __restrict__ r3,
                               const int* __restrict__ idx_i,
                               const int* __restrict__ idx_j,
                               const int* __restrict__ start,
                               int* __restrict__ cursor,
                               int* __restrict__ sorted_j,
                               bf16* __restrict__ edata) {
    int e = blockIdx.x * blockDim.x + threadIdx.x;
    if (e >= N_EDGES) return;
    float xx = r3[e * 3 + 0];
    float yy = r3[e * 3 + 1];
    float zz = r3[e * 3 + 2];
    float d = sqrtf(xx * xx + yy * yy + zz * zz);
    float inv = 1.0f / d;
    float fc = (d < CUTOFF) ? 0.5f * (cosf(d * PI_F / CUTOFF) + 1.0f) : 0.0f;
    const float width = CUTOFF / (float)(NRBF - 1);
    const float coeff = -0.5f / (width * width);
    int i = idx_i[e];
    int pos = start[i] + atomicAdd(&cursor[i], 1);
    sorted_j[pos] = idx_j[e];
    bf16* out = edata + (size_t)pos * 24;
#pragma unroll
    for (int r = 0; r < NRBF; r++) {
        float t = d - width * (float)r;
        out[r] = __float2bfloat16(__expf(coeff * t * t) * fc);
    }
    out[20] = __float2bfloat16(fc);
    out[21] = __float2bfloat16(xx * inv);
    out[22] = __float2bfloat16(yy * inv);
    out[23] = __float2bfloat16(zz * inv);
}

// ---------------------------------------------------------------------------
// Inter MLP via MFMA: 16 atoms/block, 4 waves.
// GEMM1: H = silu(Q@W1+b1)  (16x128 @ 128x128)
// GEMM2: X = H@W2+b2        (16x128 @ 128x384) -> xbf
// ---------------------------------------------------------------------------
__global__ __launch_bounds__(256) void inter_mfma(
    const float* __restrict__ q, const bf16* __restrict__ wl,
    const float* __restrict__ b1, const float* __restrict__ b2,
    bf16* __restrict__ xbf) {
    const int t = threadIdx.x;
    const int wave = t >> 6, lane = t & 63, quad = lane >> 4, l15 = lane & 15;
    const int a0 = blockIdx.x * MT;
    __shared__ __align__(16) bf16 sA[MT * 136];
    __shared__ __align__(16) bf16 sH[MT * 136];
    for (int idx = t; idx < MT * 128; idx += 256) {
        int a = idx >> 7, f = idx & 127;
        int ga = a0 + a; if (ga > N_ATOMS - 1) ga = N_ATOMS - 1;
        sA[a * 136 + f] = __float2bfloat16(q[(size_t)ga * 128 + f]);
    }
    __syncthreads();
    const f32x4 fz = {0.0f, 0.0f, 0.0f, 0.0f};
    // GEMM1
    f32x4 acc0[2] = {fz, fz};
    const bf16* B1 = wl;
#pragma unroll
    for (int kt = 0; kt < 4; kt++) {
        bf16x8 af = *(const bf16x8*)(sA + l15 * 136 + kt * 32 + quad * 8);
#pragma unroll
        for (int n = 0; n < 2; n++) {
            int c0 = (wave * 2 + n) * 16;
            bf16x8 bfr = *(const bf16x8*)(B1 + (((kt * 4 + quad) * 128) + c0 + l15) * 8);
            acc0[n] = MFMA(af, bfr, acc0[n]);
        }
    }
#pragma unroll
    for (int n = 0; n < 2; n++) {
        int col = (wave * 2 + n) * 16 + l15;
        float bb = b1[col];
#pragma unroll
        for (int r = 0; r < 4; r++) {
            int row = quad * 4 + r;
            sH[row * 136 + col] = __float2bfloat16(siluf(acc0[n][r] + bb));
        }
    }
    __syncthreads();
    // GEMM2
    f32x4 acc2[6] = {fz, fz, fz, fz, fz, fz};
    const bf16* B2 = wl + 16384;
#pragma unroll
    for (int kt = 0; kt < 4; kt++) {
        bf16x8 af = *(const bf16x8*)(sH + l15 * 136 + kt * 32 + quad * 8);
#pragma unroll
        for (int n = 0; n < 6; n++) {
            int c0 = (wave * 6 + n) * 16;
            bf16x8 bfr = *(const bf16x8*)(B2 + (((kt * 4 + quad) * 384) + c0 + l15) * 8);
            acc2[n] = MFMA(af, bfr, acc2[n]);
        }
    }
#pragma unroll
    for (int n = 0; n < 6; n++) {
        int col = (wave * 6 + n) * 16 + l15;
        float bb = b2[col];
#pragma unroll
        for (int r = 0; r < 4; r++) {
            int row = quad * 4 + r;
            int ga = a0 + row;
            if (ga < N_ATOMS)
                xbf[(size_t)ga * 384 + col] = __float2bfloat16(acc2[n][r] + bb);
        }
    }
}

// ---------------------------------------------------------------------------
// Gather: one block (128 threads) per atom i. No atomics. (unchanged)
// ---------------------------------------------------------------------------
__global__ __launch_bounds__(128) void atom_gather(
    const int* __restrict__ start, const int* __restrict__ sorted_j,
    const bf16* __restrict__ edata,
    const bf16* __restrict__ xbf, const bf16* __restrict__ mubf,
    const float* __restrict__ fW, const float* __restrict__ fb, int layer,
    float* __restrict__ q, float* __restrict__ mu) {
    int a = blockIdx.x;
    int f = threadIdx.x;
    int c0 = layer * 3 * FDIM + f;
    float wq[21], wr[21], wm[21];
#pragma unroll
    for (int r = 0; r < NRBF; r++) {
        const float* row = fW + r * (9 * FDIM) + c0;
        wq[r] = row[0];
        wr[r] = row[FDIM];
        wm[r] = row[2 * FDIM];
    }
    wq[20] = fb[c0];
    wr[20] = fb[c0 + FDIM];
    wm[20] = fb[c0 + 2 * FDIM];

    float dq = 0.0f, dm0 = 0.0f, dm1 = 0.0f, dm2 = 0.0f;
    int s = start[a], e_end = start[a + 1];
    for (int pos = s; pos < e_end; pos++) {
        int j = sorted_j[pos];
        const uint4* edp = (const uint4*)(edata + (size_t)pos * 24);
        uint4 ua = edp[0];
        uint4 ub = edp[1];
        uint4 uc = edp[2];
        float se[24];
        se[0] = lo_bf(ua.x);  se[1] = hi_bf(ua.x);
        se[2] = lo_bf(ua.y);  se[3] = hi_bf(ua.y);
        se[4] = lo_bf(ua.z);  se[5] = hi_bf(ua.z);
        se[6] = lo_bf(ua.w);  se[7] = hi_bf(ua.w);
        se[8] = lo_bf(ub.x);  se[9] = hi_bf(ub.x);
        se[10] = lo_bf(ub.y); se[11] = hi_bf(ub.y);
        se[12] = lo_bf(ub.z); se[13] = hi_bf(ub.z);
        se[14] = lo_bf(ub.w); se[15] = hi_bf(ub.w);
        se[16] = lo_bf(uc.x); se[17] = hi_bf(uc.x);
        se[18] = lo_bf(uc.y); se[19] = hi_bf(uc.y);
        se[20] = lo_bf(uc.z); se[21] = hi_bf(uc.z);
        se[22] = lo_bf(uc.w); se[23] = hi_bf(uc.w);
        float f0 = 0.0f, f1 = 0.0f, f2 = 0.0f;
#pragma unroll
        for (int r = 0; r < 21; r++) {
            f0 += se[r] * wq[r];
            f1 += se[r] * wr[r];
            f2 += se[r] * wm[r];
        }
        size_t jb = (size_t)j * (3 * FDIM);
        float xj0 = b2f(xbf[jb + f]);
        float xj1 = b2f(xbf[jb + FDIM + f]);
        float xj2 = b2f(xbf[jb + 2 * FDIM + f]);
        float dmuR = f1 * xj1;
        float dmm = f2 * xj2;
        dq += f0 * xj0;
        dm0 += dmuR * se[21] + dmm * b2f(mubf[jb + f]);
        dm1 += dmuR * se[22] + dmm * b2f(mubf[jb + FDIM + f]);
        dm2 += dmuR * se[23] + dmm * b2f(mubf[jb + 2 * FDIM + f]);
    }
    q[(size_t)a * FDIM + f] += dq;
    size_t mbase = (size_t)a * (3 * FDIM);
    mu[mbase + f] += dm0;
    mu[mbase + FDIM + f] += dm1;
    mu[mbase + 2 * FDIM + f] += dm2;
}

// ---------------------------------------------------------------------------
// Fused per-atom update via MFMA: 16 atoms/block, 4 waves.
// mix:   MU(48x128) @ mW(128x256)        -> V,W (LDS bf16)
// pw1:   vn, sdot, ctx=[q, vn]           -> sCTX, sSD
// intra1: H2 = silu(ctx@aW1+ab1)         (16x256 @ 256x128)
// intra2: X2 = H2@aW2+ab2                (16x128 @ 128x384)
// pw2:   q += x0 + x2*sdot; mu += x1*W   -> global + mubf
// ---------------------------------------------------------------------------
__global__ __launch_bounds__(256) void update_mfma(
    float* __restrict__ q, float* __restrict__ mu, bf16* __restrict__ mubf,
    const bf16* __restrict__ wl,
    const float* __restrict__ mixb, const float* __restrict__ ib1,
    const float* __restrict__ ib2) {
    const int t = threadIdx.x;
    const int wave = t >> 6, lane = t & 63, quad = lane >> 4, l15 = lane & 15;
    const int a0 = blockIdx.x * MT;
    __shared__ __align__(16) char lds[47360];
    bf16* sMU  = (bf16*)lds;             // [48][136] phase1
    bf16* sCTX = (bf16*)lds;             // [16][264] phase3 (alias sMU)
    bf16* sH2  = (bf16*)(lds + 8448);    // [16][136] phase4
    bf16* sV   = (bf16*)(lds + 13056);   // [48][136] phase2
    bf16* sX2  = (bf16*)(lds + 13056);   // [16][392] phase5 (alias sV)
    bf16* sW   = (bf16*)(lds + 26112);   // [48][136] persistent
    float* sSD = (float*)(lds + 39168);  // [16][128] persistent

    // stage MU -> LDS bf16 (rows m = a*3 + s)
    for (int idx = t; idx < 48 * 128; idx += 256) {
        int row = idx >> 7, f = idx & 127;
        int a = row / 3, s = row - a * 3;
        int ga = a0 + a; if (ga > N_ATOMS - 1) ga = N_ATOMS - 1;
        sMU[row * 136 + f] = __float2bfloat16(mu[(size_t)ga * 384 + s * 128 + f]);
    }
    __syncthreads();
    const f32x4 fz = {0.0f, 0.0f, 0.0f, 0.0f};
    // ---- mix GEMM: M=48 (3 mtiles), N=256, K=128; wave covers 4 ntiles ----
    const bf16* BM = wl + 65536;
    bf16x8 bfr[4][4];
#pragma unroll
    for (int kt = 0; kt < 4; kt++)
#pragma unroll
        for (int n = 0; n < 4; n++) {
            int c0 = (wave * 4 + n) * 16;
            bfr[n][kt] = *(const bf16x8*)(BM + (((kt * 4 + quad) * 256) + c0 + l15) * 8);
        }
    f32x4 accm[3][4];
#pragma unroll
    for (int mt = 0; mt < 3; mt++)
#pragma unroll
        for (int n = 0; n < 4; n++) accm[mt][n] = fz;
#pragma unroll
    for (int mt = 0; mt < 3; mt++) {
#pragma unroll
        for (int kt = 0; kt < 4; kt++) {
            bf16x8 af = *(const bf16x8*)(sMU + (mt * 16 + l15) * 136 + kt * 32 + quad * 8);
#pragma unroll
            for (int n = 0; n < 4; n++)
                accm[mt][n] = MFMA(af, bfr[n][kt], accm[mt][n]);
        }
    }
    __syncthreads();  // done reading sMU (sCTX will alias it)
#pragma unroll
    for (int mt = 0; mt < 3; mt++)
#pragma unroll
        for (int n = 0; n < 4; n++) {
            int col = wave * 64 + n * 16 + l15;
            float bb = mixb[col];
#pragma unroll
            for (int r = 0; r < 4; r++) {
                int row = mt * 16 + quad * 4 + r;
                float v = accm[mt][n][r] + bb;
                if (col < 128) sV[row * 136 + col] = __float2bfloat16(v);
                else           sW[row * 136 + col - 128] = __float2bfloat16(v);
            }
        }
    __syncthreads();
    // ---- pw1: vn, sdot, ctx ----
    for (int idx = t; idx < MT * 128; idx += 256) {
        int a = idx >> 7, f = idx & 127;
        float v0 = b2f(sV[(a * 3 + 0) * 136 + f]);
        float v1 = b2f(sV[(a * 3 + 1) * 136 + f]);
        float v2 = b2f(sV[(a * 3 + 2) * 136 + f]);
        float w0 = b2f(sW[(a * 3 + 0) * 136 + f]);
        float w1 = b2f(sW[(a * 3 + 1) * 136 + f]);
        float w2 = b2f(sW[(a * 3 + 2) * 136 + f]);
        sSD[a * 128 + f] = v0 * w0 + v1 * w1 + v2 * w2;
        float vn = sqrtf(v0 * v0 + v1 * v1 + v2 * v2);
        int ga = a0 + a; if (ga > N_ATOMS - 1) ga = N_ATOMS - 1;
        sCTX[a * 264 + f] = __float2bfloat16(q[(size_t)ga * 128 + f]);
        sCTX[a * 264 + 128 + f] = __float2bfloat16(vn);
    }
    __syncthreads();
    // ---- intra1: 16x256 @ 256x128 ----
    const bf16* BA1 = wl + 98304;
    f32x4 acc1[2] = {fz, fz};
#pragma unroll
    for (int kt = 0; kt < 8; kt++) {
        bf16x8 af = *(const bf16x8*)(sCTX + l15 * 264 + kt * 32 + quad * 8);
#pragma unroll
        for (int n = 0; n < 2; n++) {
            int c0 = (wave * 2 + n) * 16;
            bf16x8 bb = *(const bf16x8*)(BA1 + (((kt * 4 + quad) * 128) + c0 + l15) * 8);
            acc1[n] = MFMA(af, bb, acc1[n]);
        }
    }
#pragma unroll
    for (int n = 0; n < 2; n++) {
        int col = (wave * 2 + n) * 16 + l15;
        float bb = ib1[col];
#pragma unroll
        for (int r = 0; r < 4; r++) {
            int row = quad * 4 + r;
            sH2[row * 136 + col] = __float2bfloat16(siluf(acc1[n][r] + bb));
        }
    }
    __syncthreads();
    // ---- intra2: 16x128 @ 128x384 ----
    const bf16* BA2 = wl + 131072;
    f32x4 acc3[6] = {fz, fz, fz, fz, fz, fz};
#pragma unroll
    for (int kt = 0; kt < 4; kt++) {
        bf16x8 af = *(const bf16x8*)(sH2 + l15 * 136 + kt * 32 + quad * 8);
#pragma unroll
        for (int n = 0; n < 6; n++) {
            int c0 = (wave * 6 + n) * 16;
            bf16x8 bb = *(const bf16x8*)(BA2 + (((kt * 4 + quad) * 384) + c0 + l15) * 8);
            acc3[n] = MFMA(af, bb, acc3[n]);
        }
    }
#pragma unroll
    for (int n = 0; n < 6; n++) {
        int col = (wave * 6 + n) * 16 + l15;
        float bb = ib2[col];
#pragma unroll
        for (int r = 0; r < 4; r++) {
            int row = quad * 4 + r;
            sX2[row * 392 + col] = __float2bfloat16(acc3[n][r] + bb);
        }
    }
    __syncthreads();
    // ---- pw2: final updates ----
    for (int idx = t; idx < MT * 128; idx += 256) {
        int a = idx >> 7, f = idx & 127;
        int ga = a0 + a;
        if (ga >= N_ATOMS) continue;
        float x0 = b2f(sX2[a * 392 + f]);
        float x1 = b2f(sX2[a * 392 + 128 + f]);
        float x2 = b2f(sX2[a * 392 + 256 + f]);
        float sd = sSD[a * 128 + f];
        q[(size_t)ga * 128 + f] += x0 + x2 * sd;
#pragma unroll
        for (int s = 0; s < 3; s++) {
            float w = b2f(sW[(a * 3 + s) * 136 + f]);
            size_t off = (size_t)ga * 384 + s * 128 + f;
            float m = mu[off] + x1 * w;
            mu[off] = m;
            mubf[off] = __float2bfloat16(m);
        }
    }
}

// ---------------------------------------------------------------------------
__global__ void writeout(const float* __restrict__ q, const float* __restrict__ mu,
                         void* __restrict__ out, const int* __restrict__ flag) {
    int idx = blockIdx.x * blockDim.x + threadIdx.x;
    const int nq = N_ATOMS * FDIM;
    const int ntot = N_ATOMS * 4 * FDIM;
    if (idx >= ntot) return;
    float v = (idx < nq) ? q[idx] : mu[idx - nq];
    if (flag[0] != 0) ((bf16*)out)[idx] = __float2bfloat16(v);
    else              ((float*)out)[idx] = v;
}

extern "C" void kernel_launch(void* const* d_in, const int* in_sizes, int n_in,
                              void* d_out, int out_size, void* d_ws, size_t ws_size,
                              hipStream_t stream) {
    const int* zn    = (const int*)d_in[14];
    const int* idx_i = (const int*)d_in[15];
    const int* idx_j = (const int*)d_in[16];

    char* base = (char*)d_ws;
    int*   flag     = (int*)base;
    float* fp       = (float*)(base + 256);
    float* q        = (float*)(base + 256 + 5926016);
    float* mu       = (float*)(base + 256 + 5926016 + 7680000);
    bf16*  xbf      = (bf16*)(base + 36646272);
    bf16*  mubf     = (bf16*)(base + 48166272);
    int*   counts   = (int*)(base + 59686272);
    int*   cursor   = (int*)(base + 59746304);
    int*   startarr = (int*)(base + 59806336);
    int*   sorted_j = (int*)(base + 59866368);
    bf16*  edata    = (bf16*)(base + 61066368);   // ends ~75.5 MB
    // packed bf16 weights alias the dead r_ij-f32 region (2.16 MB < 3.6 MB),
    // written only after scatter_kernel has consumed r3.
    bf16*  wbf      = (bf16*)fp;

    detect_dtype<<<1, 256, 0, stream>>>(d_in[0], flag);

    CvtArgs ca;
    for (int t = 0; t < 14; t++) ca.src[t] = d_in[t];
    convert_all<<<(P_TOTAL + 255) / 256, 256, 0, stream>>>(ca, fp, flag);

    const float* r3  = fp + P_RIJ;
    const float* emb = fp + P_EMB;
    const float* fW  = fp + P_FW;
    const float* fb  = fp + P_FB;

    hipMemsetAsync(counts, 0, 2 * 60032, stream);
    hist_kernel<<<(N_EDGES + 255) / 256, 256, 0, stream>>>(idx_i, counts);
    scan_kernel<<<1, 256, 0, stream>>>(counts, startarr);
    scatter_kernel<<<(N_EDGES + 255) / 256, 256, 0, stream>>>(
        r3, idx_i, idx_j, startarr, cursor, sorted_j, edata);

    // r3 now dead -> pack weights over it
    pack_w<<<(3 * WPACK_L + 255) / 256, 256, 0, stream>>>(fp, wbf);

    hipMemsetAsync(mu, 0, (size_t)N_ATOMS * 3 * FDIM * sizeof(float), stream);
    hipMemsetAsync(mubf, 0, (size_t)N_ATOMS * 3 * FDIM * sizeof(bf16), stream);
    init_q<<<(N_ATOMS * FDIM + 255) / 256, 256, 0, stream>>>(zn, emb, q);

    for (int l = 0; l < 3; l++) {
        const bf16* wl = wbf + (size_t)l * WPACK_L;
        inter_mfma<<<NBLK, 256, 0, stream>>>(
            q, wl, fp + P_IB1 + l * 128, fp + P_IB2 + l * 384, xbf);
        atom_gather<<<N_ATOMS, 128, 0, stream>>>(
            startarr, sorted_j, edata, xbf, mubf, fW, fb, l, q, mu);
        update_mfma<<<NBLK, 256, 0, stream>>>(
            q, mu, mubf, wl,
            fp + P_MB + l * 256, fp + P_AB1 + l * 128, fp + P_AB2 + l * 384);
    }

    int ntot = N_ATOMS * 4 * FDIM;
    writeout<<<(ntot + 255) / 256, 256, 0, stream>>>(q, mu, d_out, flag);
}